// Round 5
// baseline (351.843 us; speedup 1.0000x reference)
//
#include <hip/hip_runtime.h>

// CondMul: out[n] = input[n] @ w[inds[n]] + b[inds[n]]
// N=262144 rows, 1024 experts, in=out=32, fp32.
//
// R5 = R4 with the compile fix: __builtin_nontemporal_load/store require a
// NATIVE vector type (ext_vector_type), not HIP_vector_type<float,4>.
//
// Structure: zero-global-atomic counting sort (R2 lesson: ~500cyc per
// same-addr device atomic). Compute kernel in steady state (R3 lesson:
// 2048 one-iteration blocks -> 7.5% occupancy, 53us):
//  - grid 1024 = 1 block/class, launch_bounds(256,4) -> all co-resident
//  - rowids staged in LDS with w -> per-chunk chain starts at ~120cyc LDS
//  - 4 rows/lane, x loaded in two j-halves to stay under 128 VGPR
//  - nontemporal x loads / out stores (streamed once, keep L2 for w+ids)

typedef float fvec4 __attribute__((ext_vector_type(4)));

#define N_ROWS      262144
#define N_CLASSES   1024
#define IN_F        32
#define OUT_F       32
#define HB          64                 // hist/scatter blocks
#define RPB         (N_ROWS / HB)      // 4096 rows per hist block, exact
#define RL_STAGE    512                // rowids staged per super-iter

// ---------------- K1: per-block LDS histogram -> bc[b][c] ----------------
__global__ __launch_bounds__(256) void k_hist(const int4* __restrict__ inds4,
                                              int* __restrict__ bc) {
    __shared__ int h[N_CLASSES];
    const int tid = threadIdx.x;
    for (int c = tid; c < N_CLASSES; c += 256) h[c] = 0;
    __syncthreads();
    const int base4 = blockIdx.x * (RPB / 4);
#pragma unroll
    for (int k = 0; k < RPB / 4; k += 256) {
        const int4 v = inds4[base4 + k + tid];
        atomicAdd(&h[v.x], 1);
        atomicAdd(&h[v.y], 1);
        atomicAdd(&h[v.z], 1);
        atomicAdd(&h[v.w], 1);
    }
    __syncthreads();
    for (int c = tid; c < N_CLASSES; c += 256)
        bc[blockIdx.x * N_CLASSES + c] = h[c];   // coalesced
}

// ------- K2: one block, 1024 threads. Registers carry the 64-block chain -------
__global__ __launch_bounds__(1024) void k_scan(int* __restrict__ bc,
                                               int* __restrict__ cls_off) {
    __shared__ int s[N_CLASSES];
    const int c = threadIdx.x;
    int v[HB];
#pragma unroll
    for (int b = 0; b < HB; ++b)           // 64 independent coalesced loads
        v[b] = bc[b * N_CLASSES + c];
    int total = 0;
#pragma unroll
    for (int b = 0; b < HB; ++b) total += v[b];
    s[c] = total;
    __syncthreads();
    for (int off = 1; off < N_CLASSES; off <<= 1) {   // Hillis-Steele
        int t = (c >= off) ? s[c - off] : 0;
        __syncthreads();
        s[c] += t;
        __syncthreads();
    }
    const int excl = s[c] - total;
    cls_off[c] = excl;
    if (c == N_CLASSES - 1) cls_off[N_CLASSES] = s[c];
    int run = excl;                        // carry chain in registers
#pragma unroll
    for (int b = 0; b < HB; ++b) {         // 64 coalesced stores
        bc[b * N_CLASSES + c] = run;
        run += v[b];
    }
}

// ---------------- K3: scatter via per-block LDS cursors ----------------
__global__ __launch_bounds__(256) void k_scatter(const int* __restrict__ inds,
                                                 const int* __restrict__ bc,
                                                 int* __restrict__ rowids) {
    __shared__ int cur[N_CLASSES];
    const int tid = threadIdx.x;
    for (int c = tid; c < N_CLASSES; c += 256)
        cur[c] = bc[blockIdx.x * N_CLASSES + c];   // coalesced
    __syncthreads();
    const int base = blockIdx.x * RPB;
    int ind[16];
#pragma unroll
    for (int k = 0; k < 16; ++k)           // 16 independent coalesced loads
        ind[k] = inds[base + k * 256 + tid];
#pragma unroll
    for (int k = 0; k < 16; ++k) {
        const int pos = atomicAdd(&cur[ind[k]], 1);  // LDS, ~4-deep
        rowids[pos] = base + k * 256 + tid;
    }
}

// ---------------- K4: one block per class, steady-state loop ----------------
// 256 threads: oq = tid&7 (output float4 col), rg = tid>>3 (0..31).
// Chunk = 128 rows, 4 rows/lane. rowids pre-staged in LDS (int4 read per
// lane, 8-way oq broadcast). x loaded nontemporally in two j-halves
// (x[4][4] live -> fits 128 VGPR cap). Wave-level per row: 1 ds_read_b128
// (w) + 1 gather dwordx4 + 16 FMA.
__global__ __launch_bounds__(256, 4) void k_condmul(const fvec4* __restrict__ input4,
                                                    const fvec4* __restrict__ w4,
                                                    const fvec4* __restrict__ bias4,
                                                    const int* __restrict__ rowids,
                                                    const int* __restrict__ cls_off,
                                                    fvec4* __restrict__ out4) {
    __shared__ fvec4 wlds4[IN_F * 8];      // [k][oq], 4 KiB
    __shared__ int rlds[RL_STAGE];         // 2 KiB staged rowids
    const int cls = blockIdx.x;
    const int tid = threadIdx.x;

    wlds4[tid] = w4[(size_t)cls * 256 + tid];   // stage expert weights

    const int oq = tid & 7;
    const int rg = tid >> 3;
    const fvec4 bv = bias4[(size_t)cls * 8 + oq];
    const int start = cls_off[cls];
    const int count = cls_off[cls + 1] - start;

    for (int sb = 0; sb < count; sb += RL_STAGE) {
        const int nstage = min(count - sb, RL_STAGE);
        for (int i = tid; i < nstage; i += 256)
            rlds[i] = rowids[start + sb + i];    // coalesced
        __syncthreads();                          // covers wlds4 on first pass

        const int nchunk = (nstage + 127) >> 7;
        for (int ch = 0; ch < nchunk; ++ch) {
            const int rbase = ch * 128 + rg * 4;
            const int4 rr = ((const int4*)rlds)[ch * 32 + rg];  // 1 ds_read_b128
            int rows[4] = {rr.x, rr.y, rr.z, rr.w};
            bool val[4];
#pragma unroll
            for (int r = 0; r < 4; ++r) {
                val[r] = (rbase + r) < nstage;
                if (!val[r]) rows[r] = 0;        // safe address for masked lanes
            }

            fvec4 acc[4] = {bv, bv, bv, bv};
            fvec4 x[4][4];

            // ---- phase A: k = 0..15 ----
#pragma unroll
            for (int r = 0; r < 4; ++r)
#pragma unroll
                for (int j = 0; j < 4; ++j)
                    x[r][j] = __builtin_nontemporal_load(
                        &input4[(size_t)(unsigned)rows[r] * 8 + j]);
#pragma unroll
            for (int j = 0; j < 4; ++j) {
#pragma unroll
                for (int s = 0; s < 4; ++s) {
                    const fvec4 wk = wlds4[(j * 4 + s) * 8 + oq];
#pragma unroll
                    for (int r = 0; r < 4; ++r) {
                        const float xs = (s == 0) ? x[r][j].x
                                       : (s == 1) ? x[r][j].y
                                       : (s == 2) ? x[r][j].z
                                                  : x[r][j].w;
                        acc[r] += xs * wk;
                    }
                }
            }

            // ---- phase B: k = 16..31 ----
#pragma unroll
            for (int r = 0; r < 4; ++r)
#pragma unroll
                for (int j = 0; j < 4; ++j)
                    x[r][j] = __builtin_nontemporal_load(
                        &input4[(size_t)(unsigned)rows[r] * 8 + 4 + j]);
#pragma unroll
            for (int j = 0; j < 4; ++j) {
#pragma unroll
                for (int s = 0; s < 4; ++s) {
                    const fvec4 wk = wlds4[((j + 4) * 4 + s) * 8 + oq];
#pragma unroll
                    for (int r = 0; r < 4; ++r) {
                        const float xs = (s == 0) ? x[r][j].x
                                       : (s == 1) ? x[r][j].y
                                       : (s == 2) ? x[r][j].z
                                                  : x[r][j].w;
                        acc[r] += xs * wk;
                    }
                }
            }

#pragma unroll
            for (int r = 0; r < 4; ++r)
                if (val[r])
                    __builtin_nontemporal_store(
                        acc[r], &out4[(size_t)(unsigned)rows[r] * 8 + oq]);
        }
        __syncthreads();   // rlds reuse guard before next staging
    }
}

// ---------------- fallback: direct gather (used only if ws too small) ----------------
__global__ __launch_bounds__(256) void k_naive(const float* __restrict__ input,
                                               const int* __restrict__ inds,
                                               const float* __restrict__ w,
                                               const float* __restrict__ bias,
                                               float* __restrict__ out) {
    const int tid = threadIdx.x;
    const int oq = tid & 7;
    const int rg = tid >> 3;
    const int row = blockIdx.x * 32 + rg;
    if (row >= N_ROWS) return;
    const int c = inds[row];
    const float4* xin = (const float4*)(input + (size_t)row * IN_F);
    const float4* wr = (const float4*)(w + (size_t)c * IN_F * OUT_F);
    float4 acc = ((const float4*)(bias + (size_t)c * OUT_F))[oq];
#pragma unroll
    for (int j = 0; j < 8; ++j) {
        const float4 xv = xin[j];
        const float a0 = xv.x, a1 = xv.y, a2 = xv.z, a3 = xv.w;
        const float4 w0 = wr[(j * 4 + 0) * 8 + oq];
        const float4 w1 = wr[(j * 4 + 1) * 8 + oq];
        const float4 w2 = wr[(j * 4 + 2) * 8 + oq];
        const float4 w3 = wr[(j * 4 + 3) * 8 + oq];
        acc.x += a0 * w0.x; acc.y += a0 * w0.y; acc.z += a0 * w0.z; acc.w += a0 * w0.w;
        acc.x += a1 * w1.x; acc.y += a1 * w1.y; acc.z += a1 * w1.z; acc.w += a1 * w1.w;
        acc.x += a2 * w2.x; acc.y += a2 * w2.y; acc.z += a2 * w2.z; acc.w += a2 * w2.w;
        acc.x += a3 * w3.x; acc.y += a3 * w3.y; acc.z += a3 * w3.z; acc.w += a3 * w3.w;
    }
    ((float4*)(out + (size_t)row * OUT_F))[oq] = acc;
}

extern "C" void kernel_launch(void* const* d_in, const int* in_sizes, int n_in,
                              void* d_out, int out_size, void* d_ws, size_t ws_size,
                              hipStream_t stream) {
    const float* input = (const float*)d_in[0];  // [N, 32] fp32
    const int*   inds  = (const int*)d_in[1];    // [N] int32
    const float* w     = (const float*)d_in[2];  // [1024, 32, 32] fp32
    const float* bias  = (const float*)d_in[3];  // [1024, 1, 32] fp32
    float* out = (float*)d_out;                  // [N, 32] fp32

    // ws layout (ints): bc[64][1024] | cls_off[1025 (+3 pad)] | rowids[N]
    int* ws = (int*)d_ws;
    int* bc      = ws;
    int* cls_off = bc + HB * N_CLASSES;
    int* rowids  = cls_off + N_CLASSES + 1 + 3;
    const size_t need = (size_t)(HB * N_CLASSES + N_CLASSES + 4 + N_ROWS) * sizeof(int);

    if (ws_size >= need) {
        k_hist<<<HB, 256, 0, stream>>>((const int4*)inds, bc);
        k_scan<<<1, 1024, 0, stream>>>(bc, cls_off);
        k_scatter<<<HB, 256, 0, stream>>>(inds, bc, rowids);
        k_condmul<<<N_CLASSES, 256, 0, stream>>>((const fvec4*)input, (const fvec4*)w,
                                                 (const fvec4*)bias, rowids, cls_off,
                                                 (fvec4*)out);
    } else {
        k_naive<<<N_ROWS / 32, 256, 0, stream>>>(input, inds, w, bias, out);
    }
}

// Round 6
// 156.898 us; speedup vs baseline: 2.2425x; 2.2425x over previous
//
#include <hip/hip_runtime.h>

// CondMul: out[n] = input[n] @ w[inds[n]] + b[inds[n]]
// N=262144 rows, 1024 experts, in=out=32, fp32.
//
// R6 = R5 minus the two poison pills found in R5's counters:
//  - __launch_bounds__(256,4) forced VGPR=64 -> x[4][4] spilled to scratch
//    (FETCH 542MB / WRITE 242MB, ~500MB of spill round-trips). Plain
//    __launch_bounds__(256) -> compiler picks ~128-148, no spill.
//  - nontemporal hints dropped: the whole working set (~69MB) fits L3
//    (R3 FETCH was 21MB < 32MB input), nt defeats that cache.
// Structure kept: zero-global-atomic counting sort, 1 block/class,
// LDS-staged rowids, 4 rows/lane, two j-half phases (live x = 64 regs).

typedef float fvec4 __attribute__((ext_vector_type(4)));

#define N_ROWS      262144
#define N_CLASSES   1024
#define IN_F        32
#define OUT_F       32
#define HB          64                 // hist/scatter blocks
#define RPB         (N_ROWS / HB)      // 4096 rows per hist block, exact
#define RL_STAGE    512                // rowids staged per super-iter

// ---------------- K1: per-block LDS histogram -> bc[b][c] ----------------
__global__ __launch_bounds__(256) void k_hist(const int4* __restrict__ inds4,
                                              int* __restrict__ bc) {
    __shared__ int h[N_CLASSES];
    const int tid = threadIdx.x;
    for (int c = tid; c < N_CLASSES; c += 256) h[c] = 0;
    __syncthreads();
    const int base4 = blockIdx.x * (RPB / 4);
#pragma unroll
    for (int k = 0; k < RPB / 4; k += 256) {
        const int4 v = inds4[base4 + k + tid];
        atomicAdd(&h[v.x], 1);
        atomicAdd(&h[v.y], 1);
        atomicAdd(&h[v.z], 1);
        atomicAdd(&h[v.w], 1);
    }
    __syncthreads();
    for (int c = tid; c < N_CLASSES; c += 256)
        bc[blockIdx.x * N_CLASSES + c] = h[c];   // coalesced
}

// ------- K2: one block, 1024 threads. Registers carry the 64-block chain -------
__global__ __launch_bounds__(1024) void k_scan(int* __restrict__ bc,
                                               int* __restrict__ cls_off) {
    __shared__ int s[N_CLASSES];
    const int c = threadIdx.x;
    int v[HB];
#pragma unroll
    for (int b = 0; b < HB; ++b)           // 64 independent coalesced loads
        v[b] = bc[b * N_CLASSES + c];
    int total = 0;
#pragma unroll
    for (int b = 0; b < HB; ++b) total += v[b];
    s[c] = total;
    __syncthreads();
    for (int off = 1; off < N_CLASSES; off <<= 1) {   // Hillis-Steele
        int t = (c >= off) ? s[c - off] : 0;
        __syncthreads();
        s[c] += t;
        __syncthreads();
    }
    const int excl = s[c] - total;
    cls_off[c] = excl;
    if (c == N_CLASSES - 1) cls_off[N_CLASSES] = s[c];
    int run = excl;                        // carry chain in registers
#pragma unroll
    for (int b = 0; b < HB; ++b) {         // 64 coalesced stores
        bc[b * N_CLASSES + c] = run;
        run += v[b];
    }
}

// ---------------- K3: scatter via per-block LDS cursors ----------------
__global__ __launch_bounds__(256) void k_scatter(const int* __restrict__ inds,
                                                 const int* __restrict__ bc,
                                                 int* __restrict__ rowids) {
    __shared__ int cur[N_CLASSES];
    const int tid = threadIdx.x;
    for (int c = tid; c < N_CLASSES; c += 256)
        cur[c] = bc[blockIdx.x * N_CLASSES + c];   // coalesced
    __syncthreads();
    const int base = blockIdx.x * RPB;
    int ind[16];
#pragma unroll
    for (int k = 0; k < 16; ++k)           // 16 independent coalesced loads
        ind[k] = inds[base + k * 256 + tid];
#pragma unroll
    for (int k = 0; k < 16; ++k) {
        const int pos = atomicAdd(&cur[ind[k]], 1);  // LDS, ~4-deep
        rowids[pos] = base + k * 256 + tid;
    }
}

// ---------------- K4: one block per class, steady-state loop ----------------
// 256 threads: oq = tid&7 (output float4 col), rg = tid>>3 (0..31).
// Chunk = 128 rows, 4 rows/lane. rowids pre-staged in LDS (int4 read per
// lane, 8-way oq broadcast). x loaded in two j-halves (x[4][4] live = 64
// VGPR -> no spill at default allocation). Wave-level per row:
// 1 ds_read_b128 (w) + 1 gather dwordx4 + 16 FMA.
__global__ __launch_bounds__(256) void k_condmul(const fvec4* __restrict__ input4,
                                                 const fvec4* __restrict__ w4,
                                                 const fvec4* __restrict__ bias4,
                                                 const int* __restrict__ rowids,
                                                 const int* __restrict__ cls_off,
                                                 fvec4* __restrict__ out4) {
    __shared__ fvec4 wlds4[IN_F * 8];      // [k][oq], 4 KiB
    __shared__ int rlds[RL_STAGE];         // 2 KiB staged rowids
    const int cls = blockIdx.x;
    const int tid = threadIdx.x;

    wlds4[tid] = w4[(size_t)cls * 256 + tid];   // stage expert weights

    const int oq = tid & 7;
    const int rg = tid >> 3;
    const fvec4 bv = bias4[(size_t)cls * 8 + oq];
    const int start = cls_off[cls];
    const int count = cls_off[cls + 1] - start;

    for (int sb = 0; sb < count; sb += RL_STAGE) {
        const int nstage = min(count - sb, RL_STAGE);
        for (int i = tid; i < nstage; i += 256)
            rlds[i] = rowids[start + sb + i];    // coalesced
        __syncthreads();                          // covers wlds4 on first pass

        const int nchunk = (nstage + 127) >> 7;
        for (int ch = 0; ch < nchunk; ++ch) {
            const int rbase = ch * 128 + rg * 4;
            const int4 rr = ((const int4*)rlds)[ch * 32 + rg];  // 1 ds_read_b128
            int rows[4] = {rr.x, rr.y, rr.z, rr.w};
            bool val[4];
#pragma unroll
            for (int r = 0; r < 4; ++r) {
                val[r] = (rbase + r) < nstage;
                if (!val[r]) rows[r] = 0;        // safe address for masked lanes
            }

            fvec4 acc[4] = {bv, bv, bv, bv};
            fvec4 x[4][4];

            // ---- phase A: k = 0..15 ----
#pragma unroll
            for (int r = 0; r < 4; ++r)
#pragma unroll
                for (int j = 0; j < 4; ++j)
                    x[r][j] = input4[(size_t)(unsigned)rows[r] * 8 + j];
#pragma unroll
            for (int j = 0; j < 4; ++j) {
#pragma unroll
                for (int s = 0; s < 4; ++s) {
                    const fvec4 wk = wlds4[(j * 4 + s) * 8 + oq];
#pragma unroll
                    for (int r = 0; r < 4; ++r) {
                        const float xs = (s == 0) ? x[r][j].x
                                       : (s == 1) ? x[r][j].y
                                       : (s == 2) ? x[r][j].z
                                                  : x[r][j].w;
                        acc[r] += xs * wk;
                    }
                }
            }

            // ---- phase B: k = 16..31 ----
#pragma unroll
            for (int r = 0; r < 4; ++r)
#pragma unroll
                for (int j = 0; j < 4; ++j)
                    x[r][j] = input4[(size_t)(unsigned)rows[r] * 8 + 4 + j];
#pragma unroll
            for (int j = 0; j < 4; ++j) {
#pragma unroll
                for (int s = 0; s < 4; ++s) {
                    const fvec4 wk = wlds4[((j + 4) * 4 + s) * 8 + oq];
#pragma unroll
                    for (int r = 0; r < 4; ++r) {
                        const float xs = (s == 0) ? x[r][j].x
                                       : (s == 1) ? x[r][j].y
                                       : (s == 2) ? x[r][j].z
                                                  : x[r][j].w;
                        acc[r] += xs * wk;
                    }
                }
            }

#pragma unroll
            for (int r = 0; r < 4; ++r)
                if (val[r])
                    out4[(size_t)(unsigned)rows[r] * 8 + oq] = acc[r];
        }
        __syncthreads();   // rlds reuse guard before next staging
    }
}

// ---------------- fallback: direct gather (used only if ws too small) ----------------
__global__ __launch_bounds__(256) void k_naive(const float* __restrict__ input,
                                               const int* __restrict__ inds,
                                               const float* __restrict__ w,
                                               const float* __restrict__ bias,
                                               float* __restrict__ out) {
    const int tid = threadIdx.x;
    const int oq = tid & 7;
    const int rg = tid >> 3;
    const int row = blockIdx.x * 32 + rg;
    if (row >= N_ROWS) return;
    const int c = inds[row];
    const float4* xin = (const float4*)(input + (size_t)row * IN_F);
    const float4* wr = (const float4*)(w + (size_t)c * IN_F * OUT_F);
    float4 acc = ((const float4*)(bias + (size_t)c * OUT_F))[oq];
#pragma unroll
    for (int j = 0; j < 8; ++j) {
        const float4 xv = xin[j];
        const float a0 = xv.x, a1 = xv.y, a2 = xv.z, a3 = xv.w;
        const float4 w0 = wr[(j * 4 + 0) * 8 + oq];
        const float4 w1 = wr[(j * 4 + 1) * 8 + oq];
        const float4 w2 = wr[(j * 4 + 2) * 8 + oq];
        const float4 w3 = wr[(j * 4 + 3) * 8 + oq];
        acc.x += a0 * w0.x; acc.y += a0 * w0.y; acc.z += a0 * w0.z; acc.w += a0 * w0.w;
        acc.x += a1 * w1.x; acc.y += a1 * w1.y; acc.z += a1 * w1.z; acc.w += a1 * w1.w;
        acc.x += a2 * w2.x; acc.y += a2 * w2.y; acc.z += a2 * w2.z; acc.w += a2 * w2.w;
        acc.x += a3 * w3.x; acc.y += a3 * w3.y; acc.z += a3 * w3.z; acc.w += a3 * w3.w;
    }
    ((float4*)(out + (size_t)row * OUT_F))[oq] = acc;
}

extern "C" void kernel_launch(void* const* d_in, const int* in_sizes, int n_in,
                              void* d_out, int out_size, void* d_ws, size_t ws_size,
                              hipStream_t stream) {
    const float* input = (const float*)d_in[0];  // [N, 32] fp32
    const int*   inds  = (const int*)d_in[1];    // [N] int32
    const float* w     = (const float*)d_in[2];  // [1024, 32, 32] fp32
    const float* bias  = (const float*)d_in[3];  // [1024, 1, 32] fp32
    float* out = (float*)d_out;                  // [N, 32] fp32

    // ws layout (ints): bc[64][1024] | cls_off[1025 (+3 pad)] | rowids[N]
    int* ws = (int*)d_ws;
    int* bc      = ws;
    int* cls_off = bc + HB * N_CLASSES;
    int* rowids  = cls_off + N_CLASSES + 1 + 3;
    const size_t need = (size_t)(HB * N_CLASSES + N_CLASSES + 4 + N_ROWS) * sizeof(int);

    if (ws_size >= need) {
        k_hist<<<HB, 256, 0, stream>>>((const int4*)inds, bc);
        k_scan<<<1, 1024, 0, stream>>>(bc, cls_off);
        k_scatter<<<HB, 256, 0, stream>>>(inds, bc, rowids);
        k_condmul<<<N_CLASSES, 256, 0, stream>>>((const fvec4*)input, (const fvec4*)w,
                                                 (const fvec4*)bias, rowids, cls_off,
                                                 (fvec4*)out);
    } else {
        k_naive<<<N_ROWS / 32, 256, 0, stream>>>(input, inds, w, bias, out);
    }
}